// Round 5
// baseline (128.601 us; speedup 1.0000x reference)
//
#include <hip/hip_runtime.h>

// ---------------------------------------------------------------------------
//  x (10,3,250,250)
//  conv1 5x5 s2 p1 + relu -> (10,6,124,124); pool 2x2 s1 -> p1 (10,6,123,123)
//  conv2 3x3 s2 p1 + relu -> (10,15,62,62);  pool 2x2 s1 -> p2 (10,15,61,61)
//  fc1 (120,55815) relu -> (10,120)  [split-K partials + parallel reduce]
//  fc2 (84,120) relu, fc3 (1,84), qnn tanh x2 -> fs (5,)
//  RBF vs train_states (8192,5) -> K -> out (1,2)
// ---------------------------------------------------------------------------

// ===== conv1 + relu + pool fused. grid (10, 62, 2), block 256 =====
__global__ __launch_bounds__(256) void convpool1_k(
    const float* __restrict__ x, const float* __restrict__ w,
    const float* __restrict__ bias, float* __restrict__ out /*(10,6,123,123)*/) {
    const int b   = blockIdx.x;
    const int py0 = blockIdx.y * 2;
    const int px0 = blockIdx.z * 62;
    const int n_py = (123 - py0) < 2 ? (123 - py0) : 2;
    const int n_oy = n_py + 1;
    const int iy0 = 2 * py0 - 1;
    const int ix0 = 2 * px0 - 1;

    __shared__ float sx[3][9][132];   // input tile
    __shared__ float so[6][3][64];    // conv outputs
    __shared__ float sw[456];         // weights (broadcast reads)

    const int tid = threadIdx.x;

    for (int i = tid; i < 450; i += 256) sw[i] = w[i];
    for (int j = tid; j < 3 * 9 * 129; j += 256) {
        int col = j % 129;
        int r   = (j / 129) % 9;
        int ic  = j / (129 * 9);
        int ix = ix0 + col, iy = iy0 + r;
        float v = 0.f;
        if ((unsigned)ix < 250u && (unsigned)iy < 250u)
            v = x[((size_t)(b * 3 + ic) * 250 + iy) * 250 + ix];
        sx[ic][r][col] = v;
    }
    __syncthreads();

    for (int p = tid; p < n_oy * 63; p += 256) {
        int oxl = p % 63;
        int oyl = p / 63;
        if (px0 + oxl < 124) {
            float acc[6];
            #pragma unroll
            for (int o = 0; o < 6; ++o) acc[o] = bias[o];
            #pragma unroll
            for (int ic = 0; ic < 3; ++ic) {
                #pragma unroll
                for (int ky = 0; ky < 5; ++ky) {
                    const float* xr = &sx[ic][2 * oyl + ky][2 * oxl];
                    #pragma unroll
                    for (int kx = 0; kx < 5; ++kx) {
                        float xv = xr[kx];
                        #pragma unroll
                        for (int o = 0; o < 6; ++o)
                            acc[o] += sw[((o * 3 + ic) * 5 + ky) * 5 + kx] * xv;
                    }
                }
            }
            #pragma unroll
            for (int o = 0; o < 6; ++o) so[o][oyl][oxl] = fmaxf(acc[o], 0.f);
        }
    }
    __syncthreads();

    for (int j = tid; j < 6 * 2 * 62; j += 256) {
        int pxl = j % 62;
        int pyl = (j / 62) & 1;
        int oc  = j / 124;
        int px = px0 + pxl, py = py0 + pyl;
        if (pyl < n_py && px < 123) {
            float v = fmaxf(fmaxf(so[oc][pyl][pxl],     so[oc][pyl][pxl + 1]),
                            fmaxf(so[oc][pyl + 1][pxl], so[oc][pyl + 1][pxl + 1]));
            out[((size_t)(b * 6 + oc) * 123 + py) * 123 + px] = v;
        }
    }
}

// ===== conv2 + relu + pool fused. grid (10, 31, 2), block 128 =====
__global__ __launch_bounds__(128) void convpool2_k(
    const float* __restrict__ in /*(10,6,123,123)*/, const float* __restrict__ w,
    const float* __restrict__ bias, float* __restrict__ out /*(10,15,61,61)*/) {
    const int b   = blockIdx.x;
    const int py0 = blockIdx.y * 2;
    const int px0 = blockIdx.z * 31;
    const int n_py = (61 - py0) < 2 ? (61 - py0) : 2;
    const int n_oy = n_py + 1;
    const int iy0 = 2 * py0 - 1;
    const int ix0 = 2 * px0 - 1;

    __shared__ float sx[6][7][68];
    __shared__ float so[15][3][32];
    __shared__ float sw[812];

    const int tid = threadIdx.x;

    for (int i = tid; i < 810; i += 128) sw[i] = w[i];
    for (int j = tid; j < 6 * 7 * 65; j += 128) {
        int col = j % 65;
        int r   = (j / 65) % 7;
        int ic  = j / (65 * 7);
        int ix = ix0 + col, iy = iy0 + r;
        float v = 0.f;
        if ((unsigned)ix < 123u && (unsigned)iy < 123u)
            v = in[((size_t)(b * 6 + ic) * 123 + iy) * 123 + ix];
        sx[ic][r][col] = v;
    }
    __syncthreads();

    for (int p = tid; p < n_oy * 32; p += 128) {
        int oxl = p % 32;
        int oyl = p / 32;
        if (px0 + oxl < 62) {
            float acc[15];
            #pragma unroll
            for (int o = 0; o < 15; ++o) acc[o] = bias[o];
            #pragma unroll
            for (int ic = 0; ic < 6; ++ic) {
                #pragma unroll
                for (int ky = 0; ky < 3; ++ky) {
                    const float* xr = &sx[ic][2 * oyl + ky][2 * oxl];
                    #pragma unroll
                    for (int kx = 0; kx < 3; ++kx) {
                        float xv = xr[kx];
                        #pragma unroll
                        for (int o = 0; o < 15; ++o)
                            acc[o] += sw[((o * 6 + ic) * 3 + ky) * 3 + kx] * xv;
                    }
                }
            }
            #pragma unroll
            for (int o = 0; o < 15; ++o) so[o][oyl][oxl] = fmaxf(acc[o], 0.f);
        }
    }
    __syncthreads();

    for (int j = tid; j < 15 * 2 * 31; j += 128) {
        int pxl = j % 31;
        int pyl = (j / 31) & 1;
        int oc  = j / 62;
        int px = px0 + pxl, py = py0 + pyl;
        if (pyl < n_py && px < 61) {
            float v = fmaxf(fmaxf(so[oc][pyl][pxl],     so[oc][pyl][pxl + 1]),
                            fmaxf(so[oc][pyl + 1][pxl], so[oc][pyl + 1][pxl + 1]));
            out[((size_t)(b * 15 + oc) * 61 + py) * 61 + px] = v;
        }
    }
}

// ================= fc1: split-K partials =================
#define FC1_K      55815
#define FC1_CHUNK  1536
#define FC1_NC     37
#define FC1_RT     15

// grid (15, 37), block 256. Wave w owns rows rt*8 + {2w, 2w+1}.
__global__ __launch_bounds__(256) void fc1_partial_k(
    const float* __restrict__ act /*(10,K)*/,
    const float* __restrict__ w   /*(120,K)*/,
    float* __restrict__ partials  /*(37,120,10)*/) {
    int rt  = blockIdx.x;
    int c   = blockIdx.y;
    int tid = threadIdx.x;
    int wave = tid >> 6, lane = tid & 63;
    int k0 = c * FC1_CHUNK;
    int k1 = k0 + FC1_CHUNK; if (k1 > FC1_K) k1 = FC1_K;
    int r0 = rt * 8 + wave * 2;
    const float* w0 = w + (size_t)r0 * FC1_K;
    const float* w1 = w + (size_t)(r0 + 1) * FC1_K;

    float acc0[10], acc1[10];
    #pragma unroll
    for (int b = 0; b < 10; ++b) { acc0[b] = 0.f; acc1[b] = 0.f; }

    for (int k = k0 + lane; k < k1; k += 64) {
        float a[10];
        #pragma unroll
        for (int b = 0; b < 10; ++b) a[b] = act[(size_t)b * FC1_K + k];
        float wv0 = w0[k];
        float wv1 = w1[k];
        #pragma unroll
        for (int b = 0; b < 10; ++b) {
            acc0[b] += wv0 * a[b];
            acc1[b] += wv1 * a[b];
        }
    }
    #pragma unroll
    for (int b = 0; b < 10; ++b) {
        float v0 = acc0[b], v1 = acc1[b];
        for (int off = 32; off > 0; off >>= 1) {
            v0 += __shfl_down(v0, off);
            v1 += __shfl_down(v1, off);
        }
        if (lane == 0) {
            size_t base = ((size_t)c * 120 + r0) * 10;
            partials[base + b]      = v0;
            partials[base + 10 + b] = v1;
        }
    }
}

// ===== fc1 reduce: 1200 outputs over 10 blocks, fully parallel =====
__global__ __launch_bounds__(128) void fc1_reduce_k(
    const float* __restrict__ part /*(37,120,10)*/,
    const float* __restrict__ bias,
    float* __restrict__ out1 /*[b*120+row]*/) {
    int idx = blockIdx.x * 128 + threadIdx.x;
    if (idx >= 1200) return;
    int row = idx / 10, b = idx % 10;
    float s = 0.f;
    #pragma unroll
    for (int c = 0; c < FC1_NC; ++c) s += part[((size_t)c * 120 + row) * 10 + b];
    out1[b * 120 + row] = fmaxf(s + bias[row], 0.f);
}

// ===== head2: fc2 + fc3 + qnn -> fs. 1 block x 256 =====
__global__ __launch_bounds__(256) void head2_k(
    const float* __restrict__ out1 /*[b*120+row]*/,
    const float* __restrict__ fc2_w, const float* __restrict__ fc2_b,
    const float* __restrict__ fc3_w, const float* __restrict__ fc3_b,
    const float* __restrict__ qw1, const float* __restrict__ qw2,
    float* __restrict__ fs_out /*(5,)*/) {
    __shared__ float s_act[1200];
    __shared__ float s_w[84][121];   // pad 121: stride%32=25, conflict-free
    __shared__ float s_fc2[840];
    __shared__ float s_h3[10], s_s1[20];
    int tid = threadIdx.x;

    for (int i = tid; i < 1200; i += 256) s_act[i] = out1[i];
    for (int i = tid; i < 84 * 120; i += 256) {
        int j = i / 120, k = i % 120;
        s_w[j][k] = fc2_w[i];
    }
    __syncthreads();

    for (int p = tid; p < 840; p += 256) {
        int b = p / 84, j = p % 84;
        float acc = fc2_b[j];
        #pragma unroll 4
        for (int k = 0; k < 120; ++k) acc += s_act[b * 120 + k] * s_w[j][k];
        s_fc2[b * 84 + j] = fmaxf(acc, 0.f);
    }
    __syncthreads();

    if (tid < 10) {
        float acc = fc3_b[0];
        for (int j = 0; j < 84; ++j) acc += s_fc2[tid * 84 + j] * fc3_w[j];
        s_h3[tid] = acc;
    }
    __syncthreads();
    if (tid < 20) {
        float acc = 0.f;
        for (int b = 0; b < 10; ++b) acc += qw1[tid * 10 + b] * s_h3[b];
        s_s1[tid] = tanhf(acc);
    }
    __syncthreads();
    if (tid < 5) {
        float acc = 0.f;
        for (int j = 0; j < 20; ++j) acc += qw2[tid * 20 + j] * s_s1[j];
        fs_out[tid] = tanhf(acc);
    }
}

// ===== RBF classifier partials: 64 blocks x 128 (1 sample/thread) =====
__global__ __launch_bounds__(128) void cls_partial_k(
    const float* __restrict__ fs,
    const float* __restrict__ ts /*(8192,5)*/,
    const float* __restrict__ kw /*(2,8192)*/,
    float* __restrict__ partials /*(64,2)*/) {
    int tid = threadIdx.x;
    int n = blockIdx.x * 128 + tid;
    __shared__ float s_fs[5];
    if (tid < 5) s_fs[tid] = fs[tid];
    __syncthreads();
    float f0 = s_fs[0], f1 = s_fs[1], f2 = s_fs[2], f3 = s_fs[3], f4 = s_fs[4];
    const float* t = ts + (size_t)n * 5;
    float d0 = f0 - t[0], d1 = f1 - t[1], d2 = f2 - t[2], d3 = f3 - t[3], d4 = f4 - t[4];
    float Kv = expf(-(d0 * d0 + d1 * d1 + d2 * d2 + d3 * d3 + d4 * d4));
    float a0 = Kv * kw[n];
    float a1 = Kv * kw[8192 + n];
    for (int off = 32; off > 0; off >>= 1) {
        a0 += __shfl_down(a0, off);
        a1 += __shfl_down(a1, off);
    }
    __shared__ float l0[2], l1[2];
    int wave = tid >> 6, lane = tid & 63;
    if (lane == 0) { l0[wave] = a0; l1[wave] = a1; }
    __syncthreads();
    if (tid == 0) {
        partials[blockIdx.x * 2 + 0] = l0[0] + l0[1];
        partials[blockIdx.x * 2 + 1] = l1[0] + l1[1];
    }
}

__global__ void cls_final_k(const float* __restrict__ partials,
                            const float* __restrict__ kb, float* __restrict__ out) {
    int c = threadIdx.x;
    if (c < 2) {
        float acc = kb[c];
        for (int i = 0; i < 64; ++i) acc += partials[i * 2 + c];
        out[c] = acc;
    }
}

extern "C" void kernel_launch(void* const* d_in, const int* in_sizes, int n_in,
                              void* d_out, int out_size, void* d_ws, size_t ws_size,
                              hipStream_t stream) {
    const float* x        = (const float*)d_in[0];
    const float* conv1_w  = (const float*)d_in[1];
    const float* conv1_b  = (const float*)d_in[2];
    const float* conv2_w  = (const float*)d_in[3];
    const float* conv2_b  = (const float*)d_in[4];
    const float* fc1_w    = (const float*)d_in[5];
    const float* fc1_b    = (const float*)d_in[6];
    const float* fc2_w    = (const float*)d_in[7];
    const float* fc2_b    = (const float*)d_in[8];
    const float* fc3_w    = (const float*)d_in[9];
    const float* fc3_b    = (const float*)d_in[10];
    const float* qnn_w1   = (const float*)d_in[11];
    const float* qnn_w2   = (const float*)d_in[12];
    const float* tstates  = (const float*)d_in[13];
    const float* kcls_w   = (const float*)d_in[14];
    const float* kcls_b   = (const float*)d_in[15];

    float* ws = (float*)d_ws;
    float* p1       = ws;                  // 907740
    float* p2       = p1 + 907740;         // 558150
    float* fc1_part = p2 + 558150;         // 44400
    float* out1     = fc1_part + 44400;    // 1200
    float* fs       = out1 + 1200;         // 8
    float* partials = fs + 8;              // 128

    convpool1_k<<<dim3(10, 62, 2), 256, 0, stream>>>(x, conv1_w, conv1_b, p1);
    convpool2_k<<<dim3(10, 31, 2), 128, 0, stream>>>(p1, conv2_w, conv2_b, p2);
    fc1_partial_k<<<dim3(FC1_RT, FC1_NC), 256, 0, stream>>>(p2, fc1_w, fc1_part);
    fc1_reduce_k<<<10, 128, 0, stream>>>(fc1_part, fc1_b, out1);
    head2_k<<<1, 256, 0, stream>>>(out1, fc2_w, fc2_b, fc3_w, fc3_b, qnn_w1, qnn_w2, fs);
    cls_partial_k<<<64, 128, 0, stream>>>(fs, tstates, kcls_w, partials);
    cls_final_k<<<1, 64, 0, stream>>>(partials, kcls_b, (float*)d_out);
}

// Round 6
// 85.676 us; speedup vs baseline: 1.5010x; 1.5010x over previous
//
#include <hip/hip_runtime.h>

// ---------------------------------------------------------------------------
//  x (10,3,250,250)
//  conv1 5x5 s2 p1 + relu -> (10,6,124,124); pool 2x2 s1 -> p1 (10,6,123,123)
//  conv2 3x3 s2 p1 + relu -> (10,15,62,62);  pool 2x2 s1 -> p2 (10,15,61,61)
//  fc1 (120,55815) relu -> (10,120)  [split-K partials + parallel reduce]
//  fc2 (84,120) relu, fc3 (1,84), qnn tanh x2 -> fs (5,)
//  RBF vs train_states (8192,5) -> K -> out (1,2)
//
//  NOTE: conv weights are read directly from global with compile-time-uniform
//  indices -> compiler scalarizes to s_load (SGPR operand in v_fmac). Do NOT
//  stage them in LDS: that forces a vector ds_read per FMA (VGPR 52->168,
//  occupancy 20%->9.6% measured in round 5).
// ---------------------------------------------------------------------------

// ===== conv1 + relu + pool fused. grid (10, 62, 2), block 256 =====
__global__ __launch_bounds__(256) void convpool1_k(
    const float* __restrict__ x, const float* __restrict__ w,
    const float* __restrict__ bias, float* __restrict__ out /*(10,6,123,123)*/) {
    const int b   = blockIdx.x;
    const int py0 = blockIdx.y * 2;
    const int px0 = blockIdx.z * 62;
    const int n_py = (123 - py0) < 2 ? (123 - py0) : 2;
    const int n_oy = n_py + 1;
    const int iy0 = 2 * py0 - 1;
    const int ix0 = 2 * px0 - 1;

    __shared__ float sx[3][9][132];   // input tile
    __shared__ float so[6][3][64];    // conv outputs

    const int tid = threadIdx.x;

    // ---- stage 3 x 9 x 129 (coalesced, zero-padded) ----
    for (int j = tid; j < 3 * 9 * 129; j += 256) {
        int col = j % 129;
        int r   = (j / 129) % 9;
        int ic  = j / (129 * 9);
        int ix = ix0 + col, iy = iy0 + r;
        float v = 0.f;
        if ((unsigned)ix < 250u && (unsigned)iy < 250u)
            v = x[((size_t)(b * 3 + ic) * 250 + iy) * 250 + ix];
        sx[ic][r][col] = v;
    }
    __syncthreads();

    // ---- conv: each thread one (oyl, oxl) for all 6 oc ----
    for (int p = tid; p < n_oy * 63; p += 256) {
        int oxl = p % 63;
        int oyl = p / 63;
        if (px0 + oxl < 124) {
            float acc[6];
            #pragma unroll
            for (int o = 0; o < 6; ++o) acc[o] = bias[o];
            #pragma unroll
            for (int ic = 0; ic < 3; ++ic) {
                #pragma unroll
                for (int ky = 0; ky < 5; ++ky) {
                    const float* xr = &sx[ic][2 * oyl + ky][2 * oxl];
                    #pragma unroll
                    for (int kx = 0; kx < 5; ++kx) {
                        float xv = xr[kx];
                        #pragma unroll
                        for (int o = 0; o < 6; ++o)
                            acc[o] += w[((o * 3 + ic) * 5 + ky) * 5 + kx] * xv;
                    }
                }
            }
            #pragma unroll
            for (int o = 0; o < 6; ++o) so[o][oyl][oxl] = fmaxf(acc[o], 0.f);
        }
    }
    __syncthreads();

    // ---- pool 2x2 s1 + store ----
    for (int j = tid; j < 6 * 2 * 62; j += 256) {
        int pxl = j % 62;
        int pyl = (j / 62) & 1;
        int oc  = j / 124;
        int px = px0 + pxl, py = py0 + pyl;
        if (pyl < n_py && px < 123) {
            float v = fmaxf(fmaxf(so[oc][pyl][pxl],     so[oc][pyl][pxl + 1]),
                            fmaxf(so[oc][pyl + 1][pxl], so[oc][pyl + 1][pxl + 1]));
            out[((size_t)(b * 6 + oc) * 123 + py) * 123 + px] = v;
        }
    }
}

// ===== conv2 + relu + pool fused. grid (10, 31, 2), block 128 =====
__global__ __launch_bounds__(128) void convpool2_k(
    const float* __restrict__ in /*(10,6,123,123)*/, const float* __restrict__ w,
    const float* __restrict__ bias, float* __restrict__ out /*(10,15,61,61)*/) {
    const int b   = blockIdx.x;
    const int py0 = blockIdx.y * 2;
    const int px0 = blockIdx.z * 31;
    const int n_py = (61 - py0) < 2 ? (61 - py0) : 2;
    const int n_oy = n_py + 1;
    const int iy0 = 2 * py0 - 1;
    const int ix0 = 2 * px0 - 1;

    __shared__ float sx[6][7][68];
    __shared__ float so[15][3][32];

    const int tid = threadIdx.x;

    for (int j = tid; j < 6 * 7 * 65; j += 128) {
        int col = j % 65;
        int r   = (j / 65) % 7;
        int ic  = j / (65 * 7);
        int ix = ix0 + col, iy = iy0 + r;
        float v = 0.f;
        if ((unsigned)ix < 123u && (unsigned)iy < 123u)
            v = in[((size_t)(b * 6 + ic) * 123 + iy) * 123 + ix];
        sx[ic][r][col] = v;
    }
    __syncthreads();

    for (int p = tid; p < n_oy * 32; p += 128) {
        int oxl = p % 32;
        int oyl = p / 32;
        if (px0 + oxl < 62) {
            float acc[15];
            #pragma unroll
            for (int o = 0; o < 15; ++o) acc[o] = bias[o];
            #pragma unroll
            for (int ic = 0; ic < 6; ++ic) {
                #pragma unroll
                for (int ky = 0; ky < 3; ++ky) {
                    const float* xr = &sx[ic][2 * oyl + ky][2 * oxl];
                    #pragma unroll
                    for (int kx = 0; kx < 3; ++kx) {
                        float xv = xr[kx];
                        #pragma unroll
                        for (int o = 0; o < 15; ++o)
                            acc[o] += w[((o * 6 + ic) * 3 + ky) * 3 + kx] * xv;
                    }
                }
            }
            #pragma unroll
            for (int o = 0; o < 15; ++o) so[o][oyl][oxl] = fmaxf(acc[o], 0.f);
        }
    }
    __syncthreads();

    for (int j = tid; j < 15 * 2 * 31; j += 128) {
        int pxl = j % 31;
        int pyl = (j / 31) & 1;
        int oc  = j / 62;
        int px = px0 + pxl, py = py0 + pyl;
        if (pyl < n_py && px < 61) {
            float v = fmaxf(fmaxf(so[oc][pyl][pxl],     so[oc][pyl][pxl + 1]),
                            fmaxf(so[oc][pyl + 1][pxl], so[oc][pyl + 1][pxl + 1]));
            out[((size_t)(b * 15 + oc) * 61 + py) * 61 + px] = v;
        }
    }
}

// ================= fc1: split-K partials =================
#define FC1_K      55815
#define FC1_CHUNK  768
#define FC1_NC     73        // ceil(55815/768)
#define FC1_RT     15

// grid (15, 73), block 256. Wave w owns rows rt*8 + {2w, 2w+1}.
__global__ __launch_bounds__(256) void fc1_partial_k(
    const float* __restrict__ act /*(10,K)*/,
    const float* __restrict__ w   /*(120,K)*/,
    float* __restrict__ partials  /*(73,120,10)*/) {
    int rt  = blockIdx.x;
    int c   = blockIdx.y;
    int tid = threadIdx.x;
    int wave = tid >> 6, lane = tid & 63;
    int k0 = c * FC1_CHUNK;
    int k1 = k0 + FC1_CHUNK; if (k1 > FC1_K) k1 = FC1_K;
    int r0 = rt * 8 + wave * 2;
    const float* w0 = w + (size_t)r0 * FC1_K;
    const float* w1 = w + (size_t)(r0 + 1) * FC1_K;

    float acc0[10], acc1[10];
    #pragma unroll
    for (int b = 0; b < 10; ++b) { acc0[b] = 0.f; acc1[b] = 0.f; }

    for (int k = k0 + lane; k < k1; k += 64) {
        float a[10];
        #pragma unroll
        for (int b = 0; b < 10; ++b) a[b] = act[(size_t)b * FC1_K + k];
        float wv0 = w0[k];
        float wv1 = w1[k];
        #pragma unroll
        for (int b = 0; b < 10; ++b) {
            acc0[b] += wv0 * a[b];
            acc1[b] += wv1 * a[b];
        }
    }
    #pragma unroll
    for (int b = 0; b < 10; ++b) {
        float v0 = acc0[b], v1 = acc1[b];
        for (int off = 32; off > 0; off >>= 1) {
            v0 += __shfl_down(v0, off);
            v1 += __shfl_down(v1, off);
        }
        if (lane == 0) {
            size_t base = ((size_t)c * 120 + r0) * 10;
            partials[base + b]      = v0;
            partials[base + 10 + b] = v1;
        }
    }
}

// ===== fc1 reduce: 1200 outputs over 10 blocks, fully parallel =====
__global__ __launch_bounds__(128) void fc1_reduce_k(
    const float* __restrict__ part /*(73,120,10)*/,
    const float* __restrict__ bias,
    float* __restrict__ out1 /*[b*120+row]*/) {
    int idx = blockIdx.x * 128 + threadIdx.x;
    if (idx >= 1200) return;
    int row = idx / 10, b = idx % 10;
    float s = 0.f;
    #pragma unroll 8
    for (int c = 0; c < FC1_NC; ++c) s += part[((size_t)c * 120 + row) * 10 + b];
    out1[b * 120 + row] = fmaxf(s + bias[row], 0.f);
}

// ===== head2: fc2 + fc3 + qnn -> fs. 1 block x 256 =====
__global__ __launch_bounds__(256) void head2_k(
    const float* __restrict__ out1 /*[b*120+row]*/,
    const float* __restrict__ fc2_w, const float* __restrict__ fc2_b,
    const float* __restrict__ fc3_w, const float* __restrict__ fc3_b,
    const float* __restrict__ qw1, const float* __restrict__ qw2,
    float* __restrict__ fs_out /*(5,)*/) {
    __shared__ float s_act[1200];
    __shared__ float s_w[84][121];   // pad 121: conflict-free
    __shared__ float s_fc2[840];
    __shared__ float s_h3[10], s_s1[20];
    int tid = threadIdx.x;

    for (int i = tid; i < 1200; i += 256) s_act[i] = out1[i];
    for (int i = tid; i < 84 * 120; i += 256) {
        int j = i / 120, k = i % 120;
        s_w[j][k] = fc2_w[i];
    }
    __syncthreads();

    for (int p = tid; p < 840; p += 256) {
        int b = p / 84, j = p % 84;
        float acc = fc2_b[j];
        #pragma unroll 4
        for (int k = 0; k < 120; ++k) acc += s_act[b * 120 + k] * s_w[j][k];
        s_fc2[b * 84 + j] = fmaxf(acc, 0.f);
    }
    __syncthreads();

    if (tid < 10) {
        float acc = fc3_b[0];
        for (int j = 0; j < 84; ++j) acc += s_fc2[tid * 84 + j] * fc3_w[j];
        s_h3[tid] = acc;
    }
    __syncthreads();
    if (tid < 20) {
        float acc = 0.f;
        for (int b = 0; b < 10; ++b) acc += qw1[tid * 10 + b] * s_h3[b];
        s_s1[tid] = tanhf(acc);
    }
    __syncthreads();
    if (tid < 5) {
        float acc = 0.f;
        for (int j = 0; j < 20; ++j) acc += qw2[tid * 20 + j] * s_s1[j];
        fs_out[tid] = tanhf(acc);
    }
}

// ===== RBF classifier partials: 64 blocks x 128 (1 sample/thread) =====
__global__ __launch_bounds__(128) void cls_partial_k(
    const float* __restrict__ fs,
    const float* __restrict__ ts /*(8192,5)*/,
    const float* __restrict__ kw /*(2,8192)*/,
    float* __restrict__ partials /*(64,2)*/) {
    int tid = threadIdx.x;
    int n = blockIdx.x * 128 + tid;
    __shared__ float s_fs[5];
    if (tid < 5) s_fs[tid] = fs[tid];
    __syncthreads();
    float f0 = s_fs[0], f1 = s_fs[1], f2 = s_fs[2], f3 = s_fs[3], f4 = s_fs[4];
    const float* t = ts + (size_t)n * 5;
    float d0 = f0 - t[0], d1 = f1 - t[1], d2 = f2 - t[2], d3 = f3 - t[3], d4 = f4 - t[4];
    float Kv = expf(-(d0 * d0 + d1 * d1 + d2 * d2 + d3 * d3 + d4 * d4));
    float a0 = Kv * kw[n];
    float a1 = Kv * kw[8192 + n];
    for (int off = 32; off > 0; off >>= 1) {
        a0 += __shfl_down(a0, off);
        a1 += __shfl_down(a1, off);
    }
    __shared__ float l0[2], l1[2];
    int wave = tid >> 6, lane = tid & 63;
    if (lane == 0) { l0[wave] = a0; l1[wave] = a1; }
    __syncthreads();
    if (tid == 0) {
        partials[blockIdx.x * 2 + 0] = l0[0] + l0[1];
        partials[blockIdx.x * 2 + 1] = l1[0] + l1[1];
    }
}

__global__ void cls_final_k(const float* __restrict__ partials,
                            const float* __restrict__ kb, float* __restrict__ out) {
    int c = threadIdx.x;
    if (c < 2) {
        float acc = kb[c];
        for (int i = 0; i < 64; ++i) acc += partials[i * 2 + c];
        out[c] = acc;
    }
}

extern "C" void kernel_launch(void* const* d_in, const int* in_sizes, int n_in,
                              void* d_out, int out_size, void* d_ws, size_t ws_size,
                              hipStream_t stream) {
    const float* x        = (const float*)d_in[0];
    const float* conv1_w  = (const float*)d_in[1];
    const float* conv1_b  = (const float*)d_in[2];
    const float* conv2_w  = (const float*)d_in[3];
    const float* conv2_b  = (const float*)d_in[4];
    const float* fc1_w    = (const float*)d_in[5];
    const float* fc1_b    = (const float*)d_in[6];
    const float* fc2_w    = (const float*)d_in[7];
    const float* fc2_b    = (const float*)d_in[8];
    const float* fc3_w    = (const float*)d_in[9];
    const float* fc3_b    = (const float*)d_in[10];
    const float* qnn_w1   = (const float*)d_in[11];
    const float* qnn_w2   = (const float*)d_in[12];
    const float* tstates  = (const float*)d_in[13];
    const float* kcls_w   = (const float*)d_in[14];
    const float* kcls_b   = (const float*)d_in[15];

    float* ws = (float*)d_ws;
    float* p1       = ws;                  // 907740
    float* p2       = p1 + 907740;         // 558150
    float* fc1_part = p2 + 558150;         // 73*120*10 = 87600
    float* out1     = fc1_part + 87600;    // 1200
    float* fs       = out1 + 1200;         // 8
    float* partials = fs + 8;              // 128

    convpool1_k<<<dim3(10, 62, 2), 256, 0, stream>>>(x, conv1_w, conv1_b, p1);
    convpool2_k<<<dim3(10, 31, 2), 128, 0, stream>>>(p1, conv2_w, conv2_b, p2);
    fc1_partial_k<<<dim3(FC1_RT, FC1_NC), 256, 0, stream>>>(p2, fc1_w, fc1_part);
    fc1_reduce_k<<<10, 128, 0, stream>>>(fc1_part, fc1_b, out1);
    head2_k<<<1, 256, 0, stream>>>(out1, fc2_w, fc2_b, fc3_w, fc3_b, qnn_w1, qnn_w2, fs);
    cls_partial_k<<<64, 128, 0, stream>>>(fs, tstates, kcls_w, partials);
    cls_final_k<<<1, 64, 0, stream>>>(partials, kcls_b, (float*)d_out);
}